// Round 12
// baseline (14170.341 us; speedup 1.0000x reference)
//
#include <hip/hip_runtime.h>
#include <hip/hip_bf16.h>

#define S_LEN 50
#define T_LEN 50
#define BATCH 128
#define EMB 300
#define ENC_H 512
#define DEC_H 1024
#define TRG_V 23262
#define DEC_IN (DEC_H + EMB)      // 1324
#define KCAT (DEC_IN + DEC_H)     // 2348
#define GN (4 * DEC_H)            // 4096

static inline int cdiv(int a, int b) { return (a + b - 1) / b; }

__device__ __forceinline__ float sigm(float x) { return 1.f / (1.f + expf(-x)); }

typedef __attribute__((ext_vector_type(8))) short bf16x8;
typedef __attribute__((ext_vector_type(4))) float f32x4;

__device__ __forceinline__ void gload_lds16(const void* g, void* l) {
    __builtin_amdgcn_global_load_lds((const __attribute__((address_space(1))) int*)g,
                                     (__attribute__((address_space(3))) int*)l, 16, 0, 0);
}

// ---------------- grid barrier: device-scope atomic-RMW poll ----------------
// Poll with atomicAdd(cnt,0): executes at the coherence point (LLC), always
// sees the current count (per-XCD L2s are not cross-coherent, so a plain
// relaxed load can spin on a stale line), and does not invalidate local caches
// (unlike an acquire-per-poll load).
__device__ __forceinline__ void gbar(unsigned* cnt, unsigned target) {
    __syncthreads();
    if (threadIdx.x == 0) {
        __threadfence();                 // release my block's writes
        atomicAdd(cnt, 1u);
        while (atomicAdd(cnt, 0u) < target)
            __builtin_amdgcn_s_sleep(32);
        __threadfence();                 // acquire after exit
    }
    __syncthreads();
}

// ---------------- MFMA bf16 GEMM (generator): C = A @ W^T + bias ----------------
__global__ __launch_bounds__(256)
void gemm_mfma_bf16(const __hip_bfloat16* __restrict__ A, const __hip_bfloat16* __restrict__ W,
                    const float* __restrict__ bias, float* __restrict__ C,
                    int M, int N, int K, int ldc)
{
    __shared__ short As[128 * 32];
    __shared__ short Bs[128 * 32];
    const int tid  = threadIdx.x;
    const int wave = tid >> 6;
    const int lane = tid & 63;
    const int m0 = blockIdx.y * 128;
    const int n0 = blockIdx.x * 128;
    const int wr = wave >> 1, wc = wave & 1;

    const int srow = lane >> 2;
    const int kgrp = lane & 3;
    const int arow0 = 32 * wave;

    f32x4 acc[4][4] = {};

    for (int k0 = 0; k0 < K; k0 += 32) {
#pragma unroll
        for (int c = 0; c < 2; c++) {
            int row = arow0 + 16 * c + srow;
            gload_lds16(A + (size_t)(m0 + row) * K + k0 + kgrp * 8,
                        &As[(arow0 + 16 * c) * 32]);
        }
#pragma unroll
        for (int c = 0; c < 2; c++) {
            int row = arow0 + 16 * c + srow;
            int gr = n0 + row; if (gr > N - 1) gr = N - 1;
            gload_lds16(W + (size_t)gr * K + k0 + kgrp * 8,
                        &Bs[(arow0 + 16 * c) * 32]);
        }
        __syncthreads();

        bf16x8 a[4], b[4];
#pragma unroll
        for (int mi = 0; mi < 4; mi++)
            a[mi] = *(const bf16x8*)&As[(wr * 64 + mi * 16 + (lane & 15)) * 32 + (lane >> 4) * 8];
#pragma unroll
        for (int ni = 0; ni < 4; ni++)
            b[ni] = *(const bf16x8*)&Bs[(wc * 64 + ni * 16 + (lane & 15)) * 32 + (lane >> 4) * 8];
#pragma unroll
        for (int mi = 0; mi < 4; mi++)
#pragma unroll
            for (int ni = 0; ni < 4; ni++)
                acc[mi][ni] = __builtin_amdgcn_mfma_f32_16x16x32_bf16(a[mi], b[ni], acc[mi][ni], 0, 0, 0);
        __syncthreads();
    }

#pragma unroll
    for (int mi = 0; mi < 4; mi++)
#pragma unroll
        for (int ni = 0; ni < 4; ni++) {
            int col = n0 + wc * 64 + ni * 16 + (lane & 15);
            if (col >= N) continue;
            float bv = bias[col];
#pragma unroll
            for (int r = 0; r < 4; r++) {
                int row = m0 + wr * 64 + mi * 16 + (lane >> 4) * 4 + r;
                C[(size_t)row * ldc + col] = acc[mi][ni][r] + bv;
            }
        }
}

__global__ void cast_f32_bf16(const float* __restrict__ in, __hip_bfloat16* __restrict__ out, size_t n)
{
    size_t i = ((size_t)blockIdx.x * blockDim.x + threadIdx.x) * 4;
    if (i + 3 < n) {
        float4 v = *(const float4*)(in + i);
        out[i + 0] = __float2bfloat16(v.x);
        out[i + 1] = __float2bfloat16(v.y);
        out[i + 2] = __float2bfloat16(v.z);
        out[i + 3] = __float2bfloat16(v.w);
    } else {
        for (; i < n; i++) out[i] = __float2bfloat16(in[i]);
    }
}

// ---------------- generic fp32 GEMM (big, 128x128 tiles): C = A @ W^T (+bias) ----------------
template<int BM, int BN, int BK, int TM, int TN, bool HAS_BIAS>
__global__ __launch_bounds__((BM / TM) * (BN / TN))
void gemm_bt(const float* __restrict__ A, const float* __restrict__ W,
             const float* __restrict__ bias, float* __restrict__ C,
             int M, int N, int K, int ldc)
{
    constexpr int NT  = (BM / TM) * (BN / TN);
    constexpr int NGA = TM / 4;
    constexpr int NGB = TN / 4;
    constexpr int GS  = (BN / TN) * 4;
    constexpr int LPA = BM * BK / 4 / NT;
    constexpr int LPB = BN * BK / 4 / NT;

    __shared__ float As[BK][BM + 4];
    __shared__ float Bs[BK][BN + 4];

    const int tid = threadIdx.x;
    const int tx = tid % (BN / TN);
    const int ty = tid / (BN / TN);
    const int m0 = blockIdx.y * BM;
    const int n0 = blockIdx.x * BN;

    float acc[TM][TN];
#pragma unroll
    for (int i = 0; i < TM; i++)
#pragma unroll
        for (int j = 0; j < TN; j++) acc[i][j] = 0.f;

    for (int k0 = 0; k0 < K; k0 += BK) {
#pragma unroll
        for (int e = 0; e < LPA; e++) {
            int idx = tid + e * NT;
            int r = idx / (BK / 4);
            int c4 = idx % (BK / 4);
            int row = m0 + r; if (row > M - 1) row = M - 1;
            int kk = k0 + c4 * 4;
            float4 v;
            if (kk + 3 < K) {
                v = *(const float4*)(A + (size_t)row * K + kk);
            } else {
                v.x = (kk + 0 < K) ? A[(size_t)row * K + kk + 0] : 0.f;
                v.y = (kk + 1 < K) ? A[(size_t)row * K + kk + 1] : 0.f;
                v.z = (kk + 2 < K) ? A[(size_t)row * K + kk + 2] : 0.f;
                v.w = (kk + 3 < K) ? A[(size_t)row * K + kk + 3] : 0.f;
            }
            As[c4 * 4 + 0][r] = v.x; As[c4 * 4 + 1][r] = v.y;
            As[c4 * 4 + 2][r] = v.z; As[c4 * 4 + 3][r] = v.w;
        }
#pragma unroll
        for (int e = 0; e < LPB; e++) {
            int idx = tid + e * NT;
            int r = idx / (BK / 4);
            int c4 = idx % (BK / 4);
            int row = n0 + r; if (row > N - 1) row = N - 1;
            int kk = k0 + c4 * 4;
            float4 v;
            if (kk + 3 < K) {
                v = *(const float4*)(W + (size_t)row * K + kk);
            } else {
                v.x = (kk + 0 < K) ? W[(size_t)row * K + kk + 0] : 0.f;
                v.y = (kk + 1 < K) ? W[(size_t)row * K + kk + 1] : 0.f;
                v.z = (kk + 2 < K) ? W[(size_t)row * K + kk + 2] : 0.f;
                v.w = (kk + 3 < K) ? W[(size_t)row * K + kk + 3] : 0.f;
            }
            Bs[c4 * 4 + 0][r] = v.x; Bs[c4 * 4 + 1][r] = v.y;
            Bs[c4 * 4 + 2][r] = v.z; Bs[c4 * 4 + 3][r] = v.w;
        }
        __syncthreads();
#pragma unroll
        for (int kk = 0; kk < BK; kk++) {
            float a[TM], b[TN];
#pragma unroll
            for (int g = 0; g < NGA; g++) {
                float4 v = *(const float4*)(&As[kk][ty * TM + g * 4]);
                a[g * 4 + 0] = v.x; a[g * 4 + 1] = v.y; a[g * 4 + 2] = v.z; a[g * 4 + 3] = v.w;
            }
#pragma unroll
            for (int g = 0; g < NGB; g++) {
                float4 v = *(const float4*)(&Bs[kk][tx * 4 + g * GS]);
                b[g * 4 + 0] = v.x; b[g * 4 + 1] = v.y; b[g * 4 + 2] = v.z; b[g * 4 + 3] = v.w;
            }
#pragma unroll
            for (int i = 0; i < TM; i++)
#pragma unroll
                for (int j = 0; j < TN; j++)
                    acc[i][j] = fmaf(a[i], b[j], acc[i][j]);
        }
        __syncthreads();
    }

#pragma unroll
    for (int i = 0; i < TM; i++) {
        int row = m0 + ty * TM + i;
        if (row >= M) continue;
#pragma unroll
        for (int g = 0; g < NGB; g++) {
            int colb = n0 + tx * 4 + g * GS;
#pragma unroll
            for (int j = 0; j < 4; j++) {
                int cc = colb + j;
                if (cc >= N) continue;
                float v = acc[i][g * 4 + j];
                if (HAS_BIAS) v += bias[cc];
                C[(size_t)row * ldc + cc] = v;
            }
        }
    }
}

// ---------------- 32x64-tile fp32 GEMM core (dbuf + register prefetch) ----------------
__device__ __forceinline__ float4 g4k(const float* base, int kk, int K) {
    float4 v = make_float4(0.f, 0.f, 0.f, 0.f);
    if (kk + 3 < K) v = *(const float4*)(base + kk);
    else {
        if (kk     < K) v.x = base[kk];
        if (kk + 1 < K) v.y = base[kk + 1];
        if (kk + 2 < K) v.z = base[kk + 2];
    }
    return v;
}

__device__ __forceinline__ void tile_core(
    float (&As)[2][32][36], float (&Bs)[2][32][68],
    const float* __restrict__ A, int lda,
    const float* __restrict__ W, int ldw, int K,
    int m0, int n0, float (&acc)[2][4])
{
    const int tid = threadIdx.x;
    const int tx = tid & 15, ty = tid >> 4;
    const int ar = tid >> 3, ac4 = tid & 7;
    const float* abase = A + (size_t)(m0 + ar) * lda;
    const float* bb0   = W + (size_t)(n0 + ar) * ldw;
    const float* bb1   = bb0 + (size_t)32 * ldw;

    acc[0][0]=acc[0][1]=acc[0][2]=acc[0][3]=0.f;
    acc[1][0]=acc[1][1]=acc[1][2]=acc[1][3]=0.f;
    const int NIT = (K + 31) / 32;

    {
        int kk = ac4 * 4;  // K >= 32 always here
        float4 pa  = *(const float4*)(abase + kk);
        float4 pb0 = *(const float4*)(bb0 + kk);
        float4 pb1 = *(const float4*)(bb1 + kk);
        *(float4*)&As[0][ar][ac4 * 4] = pa;
        Bs[0][ac4*4+0][ar]    = pb0.x; Bs[0][ac4*4+1][ar]    = pb0.y;
        Bs[0][ac4*4+2][ar]    = pb0.z; Bs[0][ac4*4+3][ar]    = pb0.w;
        Bs[0][ac4*4+0][ar+32] = pb1.x; Bs[0][ac4*4+1][ar+32] = pb1.y;
        Bs[0][ac4*4+2][ar+32] = pb1.z; Bs[0][ac4*4+3][ar+32] = pb1.w;
    }
    __syncthreads();

    int cur = 0;
    for (int it = 0; it < NIT; ++it) {
        float4 qa, qb0, qb1;
        const bool has = (it + 1 < NIT);
        if (has) {
            int k0 = (it + 1) * 32;
            int kk = k0 + ac4 * 4;
            if (k0 + 32 <= K) { qa = *(const float4*)(abase + kk); qb0 = *(const float4*)(bb0 + kk); qb1 = *(const float4*)(bb1 + kk); }
            else { qa = g4k(abase, kk, K); qb0 = g4k(bb0, kk, K); qb1 = g4k(bb1, kk, K); }
        }
#pragma unroll
        for (int k4 = 0; k4 < 8; ++k4) {
            float4 a0 = *(const float4*)&As[cur][ty*2+0][k4*4];
            float4 a1 = *(const float4*)&As[cur][ty*2+1][k4*4];
            float4 b0 = *(const float4*)&Bs[cur][k4*4+0][tx*4];
            float4 b1 = *(const float4*)&Bs[cur][k4*4+1][tx*4];
            float4 b2 = *(const float4*)&Bs[cur][k4*4+2][tx*4];
            float4 b3 = *(const float4*)&Bs[cur][k4*4+3][tx*4];
            float av0[4] = {a0.x, a0.y, a0.z, a0.w};
            float av1[4] = {a1.x, a1.y, a1.z, a1.w};
            float4 bq[4] = {b0, b1, b2, b3};
#pragma unroll
            for (int q = 0; q < 4; q++) {
                acc[0][0] = fmaf(av0[q], bq[q].x, acc[0][0]);
                acc[0][1] = fmaf(av0[q], bq[q].y, acc[0][1]);
                acc[0][2] = fmaf(av0[q], bq[q].z, acc[0][2]);
                acc[0][3] = fmaf(av0[q], bq[q].w, acc[0][3]);
                acc[1][0] = fmaf(av1[q], bq[q].x, acc[1][0]);
                acc[1][1] = fmaf(av1[q], bq[q].y, acc[1][1]);
                acc[1][2] = fmaf(av1[q], bq[q].z, acc[1][2]);
                acc[1][3] = fmaf(av1[q], bq[q].w, acc[1][3]);
            }
        }
        if (has) {
            int nb = cur ^ 1;
            *(float4*)&As[nb][ar][ac4 * 4] = qa;
            Bs[nb][ac4*4+0][ar]    = qb0.x; Bs[nb][ac4*4+1][ar]    = qb0.y;
            Bs[nb][ac4*4+2][ar]    = qb0.z; Bs[nb][ac4*4+3][ar]    = qb0.w;
            Bs[nb][ac4*4+0][ar+32] = qb1.x; Bs[nb][ac4*4+1][ar+32] = qb1.y;
            Bs[nb][ac4*4+2][ar+32] = qb1.z; Bs[nb][ac4*4+3][ar+32] = qb1.w;
        }
        __syncthreads();
        cur ^= 1;
    }
}

// ---------------- attention body (one block per batch row; s_tilde only) ----------------
__device__ __forceinline__ void attn_body(
    int b, float* hv, float* sc,
    const float* __restrict__ encP, const float* __restrict__ enc_out,
    float* __restrict__ attn_cat)
{
    const int tid = threadIdx.x;
    for (int d = tid; d < DEC_H; d += 256) hv[d] = attn_cat[(size_t)b * 2 * DEC_H + DEC_H + d];
    __syncthreads();
    int wave = tid >> 6, lane = tid & 63;
    for (int s = wave; s < S_LEN; s += 4) {
        const float* e = encP + ((size_t)s * BATCH + b) * DEC_H;
        float p = 0.f;
        for (int d = lane; d < DEC_H; d += 64) p = fmaf(e[d], hv[d], p);
        for (int off = 32; off; off >>= 1) p += __shfl_down(p, off);
        if (lane == 0) sc[s] = p;
    }
    __syncthreads();
    if (tid < 64) {
        float x = (tid < S_LEN) ? sc[tid] : -1e30f;
        float m = x;
        for (int off = 32; off; off >>= 1) m = fmaxf(m, __shfl_xor(m, off));
        float ex = (tid < S_LEN) ? expf(x - m) : 0.f;
        float ssum = ex;
        for (int off = 32; off; off >>= 1) ssum += __shfl_xor(ssum, off);
        if (tid < S_LEN) sc[tid] = ex / ssum;
    }
    __syncthreads();
    for (int d = tid; d < DEC_H; d += 256) {
        float a = 0.f;
#pragma unroll 5
        for (int s = 0; s < S_LEN; s++)
            a = fmaf(sc[s], enc_out[((size_t)s * BATCH + b) * DEC_H + d], a);
        attn_cat[(size_t)b * 2 * DEC_H + d] = a;
    }
}

// ---------------- persistent encoder: 50 steps, 1 barrier/step ----------------
__global__ __launch_bounds__(256)
void enc_persistent(const float* __restrict__ Gf, const float* __restrict__ Gr,
                    const float* __restrict__ whhF, const float* __restrict__ whhR,
                    float* __restrict__ hF2, float* __restrict__ hR2,
                    float* __restrict__ cF, float* __restrict__ cR,
                    float* __restrict__ enc_out, unsigned* __restrict__ barcnt)
{
    __shared__ struct { float As[2][32][36]; float Bs[2][32][68]; } sm;
    const int blk = blockIdx.x;
    const int tid = threadIdx.x;
    const int tx = tid & 15, ty = tid >> 4;
    const int dir = blk >> 7;
    const int id  = blk & 127;
    const int m0 = (id >> 5) * 32;
    const int n0 = (id & 31) * 64;
    const float* W  = dir ? whhR : whhF;
    float* cst      = dir ? cR : cF;
    float* hbase    = dir ? hR2 : hF2;
    const float* G  = dir ? Gr : Gf;
    const int HS = BATCH * ENC_H;
    unsigned epoch = 0;
    float acc[2][4];

    for (int t = 0; t < S_LEN; ++t) {
        const float* h_in = hbase + (size_t)(t & 1) * HS;
        float* h_out      = hbase + (size_t)((t + 1) & 1) * HS;
        int s_g = dir ? (S_LEN - 1 - t) : t;
        const float* D = G + (size_t)s_g * BATCH * 4 * ENC_H;

        tile_core(sm.As, sm.Bs, h_in, ENC_H, W, ENC_H, ENC_H, m0, n0, acc);

        int cb = n0 + tx * 4, j = cb >> 2;
#pragma unroll
        for (int i = 0; i < 2; i++) {
            int b = m0 + ty * 2 + i;
            float4 d4 = *(const float4*)(D + (size_t)b * 4 * ENC_H + cb);
            float gi = acc[i][0] + d4.x, gf = acc[i][1] + d4.y;
            float gg = acc[i][2] + d4.z, go = acc[i][3] + d4.w;
            float c2 = sigm(gf) * cst[b * ENC_H + j] + sigm(gi) * tanhf(gg);
            float h2 = sigm(go) * tanhf(c2);
            cst[b * ENC_H + j] = c2;
            h_out[b * ENC_H + j] = h2;
            enc_out[((size_t)s_g * BATCH + b) * DEC_H + dir * ENC_H + j] = h2;
        }
        if (t < S_LEN - 1) gbar(barcnt, 256u * (++epoch));
    }
}

// ---------------- persistent decoder: 49 steps x 3 balanced phases ----------------
// gates split: gates = catA[ct]*Wc^T (phase C) + catA[emb|h]*Whe^T (gpart, phases A+B)
__global__ __launch_bounds__(256)
void dec_persistent(const float* __restrict__ encP, const float* __restrict__ enc_out,
                    const int* __restrict__ trg, const float* __restrict__ DEMB,
                    const float* __restrict__ aWo, const float* __restrict__ wcat,
                    const float* __restrict__ db_i,
                    float* __restrict__ attn_cat, float* __restrict__ catA,
                    float* __restrict__ cdec, float* __restrict__ gpart,
                    __hip_bfloat16* __restrict__ H_bf, unsigned* __restrict__ barcnt)
{
    __shared__ union {
        struct { float hv[DEC_H]; float sc[S_LEN]; } a;
        struct { float As[2][32][36]; float Bs[2][32][68]; } g;
    } sm;
    const int blk = blockIdx.x;
    const int tid = threadIdx.x;
    const int tx = tid & 15, ty = tid >> 4;
    unsigned epoch = 0;
    float acc[2][4];

    for (int t = 0; t < T_LEN - 1; ++t) {
        // ---- Phase A: attn (0-127) || aWo_h partial (128-191) || gates-hemb tiles 0-63 (192-255)
        if (blk < 128) {
            attn_body(blk, sm.a.hv, sm.a.sc, encP, enc_out, attn_cat);
        } else if (blk < 192) {
            int id = blk - 128;
            int m0 = (id >> 4) * 32, n0 = (id & 15) * 64;
            tile_core(sm.g.As, sm.g.Bs, attn_cat + DEC_H, 2 * DEC_H,
                      aWo + DEC_H, 2 * DEC_H, DEC_H, m0, n0, acc);
            int cb = n0 + tx * 4;
#pragma unroll
            for (int i = 0; i < 2; i++) {
                int row = m0 + ty * 2 + i;
                float* dst = catA + (size_t)row * KCAT + cb;
                dst[0] = acc[i][0]; dst[1] = acc[i][1];
                dst[2] = acc[i][2]; dst[3] = acc[i][3];
            }
        } else {
            int tau = blk - 192;                    // tiles 0..63
            int m0 = (tau >> 6) * 32, n0 = (tau & 63) * 64;
            tile_core(sm.g.As, sm.g.Bs, catA + DEC_H, KCAT,
                      wcat + DEC_H, KCAT, KCAT - DEC_H, m0, n0, acc);
            int cb = n0 + tx * 4;
#pragma unroll
            for (int i = 0; i < 2; i++) {
                int row = m0 + ty * 2 + i;
                float* dst = gpart + (size_t)row * GN + cb;
                dst[0] = acc[i][0]; dst[1] = acc[i][1];
                dst[2] = acc[i][2]; dst[3] = acc[i][3];
            }
        }
        gbar(barcnt, 256u * (++epoch));

        // ---- Phase B: aWo_s~ + add + tanh (0-63) || gates-hemb tiles 64-255 (64-255)
        if (blk < 64) {
            int m0 = (blk >> 4) * 32, n0 = (blk & 15) * 64;
            tile_core(sm.g.As, sm.g.Bs, attn_cat, 2 * DEC_H, aWo, 2 * DEC_H, DEC_H, m0, n0, acc);
            int cb = n0 + tx * 4;
#pragma unroll
            for (int i = 0; i < 2; i++) {
                int row = m0 + ty * 2 + i;
                float* dst = catA + (size_t)row * KCAT + cb;
                dst[0] = tanhf(acc[i][0] + dst[0]); dst[1] = tanhf(acc[i][1] + dst[1]);
                dst[2] = tanhf(acc[i][2] + dst[2]); dst[3] = tanhf(acc[i][3] + dst[3]);
            }
        } else {
            int tau = blk;                          // tiles 64..255
            int m0 = (tau >> 6) * 32, n0 = (tau & 63) * 64;
            tile_core(sm.g.As, sm.g.Bs, catA + DEC_H, KCAT,
                      wcat + DEC_H, KCAT, KCAT - DEC_H, m0, n0, acc);
            int cb = n0 + tx * 4;
#pragma unroll
            for (int i = 0; i < 2; i++) {
                int row = m0 + ty * 2 + i;
                float* dst = gpart + (size_t)row * GN + cb;
                dst[0] = acc[i][0]; dst[1] = acc[i][1];
                dst[2] = acc[i][2]; dst[3] = acc[i][3];
            }
        }
        gbar(barcnt, 256u * (++epoch));

        // ---- Phase C: gates-ct (K=1024) + gpart + bias + LSTM epilogue (all 256)
        {
            int m0 = (blk >> 6) * 32, n0 = (blk & 63) * 64;
            tile_core(sm.g.As, sm.g.Bs, catA, KCAT, wcat, KCAT, DEC_H, m0, n0, acc);
            int cb = n0 + tx * 4, j = cb >> 2;
            float4 bz = *(const float4*)(db_i + cb);
#pragma unroll
            for (int i = 0; i < 2; i++) {
                int b = m0 + ty * 2 + i;
                float4 gp = *(const float4*)(gpart + (size_t)b * GN + cb);
                float gi = acc[i][0] + gp.x + bz.x, gf = acc[i][1] + gp.y + bz.y;
                float gg = acc[i][2] + gp.z + bz.z, go = acc[i][3] + gp.w + bz.w;
                float c2 = sigm(gf) * cdec[b * DEC_H + j] + sigm(gi) * tanhf(gg);
                float h2 = sigm(go) * tanhf(c2);
                cdec[b * DEC_H + j] = c2;
                H_bf[(size_t)t * BATCH * DEC_H + b * DEC_H + j] = __float2bfloat16(h2);
                attn_cat[(size_t)b * 2 * DEC_H + DEC_H + j] = h2;
                catA[(size_t)b * KCAT + DEC_IN + j] = h2;
            }
            // stage next step's target embedding (blocks with n0==0; rows m0..m0+31)
            if ((blk & 63) == 0 && t + 1 < T_LEN - 1) {
                for (int idx = tid; idx < 32 * EMB; idx += 256) {
                    int r = m0 + idx / EMB, e = idx % EMB;
                    int idt = trg[(t + 1) * BATCH + r];
                    catA[(size_t)r * KCAT + DEC_H + e] = DEMB[(size_t)idt * EMB + e];
                }
            }
        }
        if (t < T_LEN - 2) gbar(barcnt, 256u * (++epoch));
    }
}

// ---------------- small kernels ----------------
__global__ void zero_f32(float* p, size_t n) {
    size_t i = (size_t)blockIdx.x * blockDim.x + threadIdx.x;
    if (i < n) p[i] = 0.f;
}

__global__ void gather_rows(const int* __restrict__ ids, const float* __restrict__ E,
                            float* __restrict__ out, int nrows, int width)
{
    size_t i = (size_t)blockIdx.x * blockDim.x + threadIdx.x;
    size_t total = (size_t)nrows * width;
    if (i >= total) return;
    int r = (int)(i / width);
    int e = (int)(i % width);
    out[i] = E[(size_t)ids[r] * width + e];
}

__global__ void interleave_rows(const float* __restrict__ src, float* __restrict__ dst,
                                int units, int kdim)
{
    size_t i = (size_t)blockIdx.x * blockDim.x + threadIdx.x;
    size_t total = (size_t)4 * units * kdim;
    if (i >= total) return;
    int ir = (int)(i / kdim), k = (int)(i % kdim);
    int gate = ir & 3, j = ir >> 2;
    dst[i] = src[(size_t)(gate * units + j) * kdim + k];
}

__global__ void interleave_vec(const float* __restrict__ src, float* __restrict__ dst, int units)
{
    int i = blockIdx.x * blockDim.x + threadIdx.x;
    if (i >= 4 * units) return;
    int gate = i & 3, j = i >> 2;
    dst[i] = src[gate * units + j];
}

__global__ void build_wcat_int(const float* __restrict__ Wih, const float* __restrict__ Whh,
                               float* __restrict__ dst)
{
    size_t i = (size_t)blockIdx.x * blockDim.x + threadIdx.x;
    if (i >= (size_t)4 * DEC_H * KCAT) return;
    int ir = (int)(i / KCAT), k = (int)(i % KCAT);
    int gate = ir & 3, j = ir >> 2;
    int r = gate * DEC_H + j;
    dst[i] = (k < DEC_IN) ? Wih[(size_t)r * DEC_IN + k] : Whh[(size_t)r * DEC_H + (k - DEC_IN)];
}

__global__ void transpose_sq(const float* __restrict__ src, float* __restrict__ dst, int n)
{
    int i = blockIdx.x * blockDim.x + threadIdx.x;
    if (i >= n * n) return;
    int r = i / n, c = i % n;
    dst[(size_t)r * n + c] = src[(size_t)c * n + r];
}

// decoder init: h0/c0 interleave into attn_cat[h], catA[h], cdec; stage emb t=0
__global__ void dec_init2(const float* __restrict__ hF, const float* __restrict__ cF,
                          const float* __restrict__ hR, const float* __restrict__ cR,
                          const int* __restrict__ trg, const float* __restrict__ DEMB,
                          float* __restrict__ attn_cat, float* __restrict__ catA,
                          float* __restrict__ cdec)
{
    int idx = blockIdx.x * blockDim.x + threadIdx.x;
    if (idx < BATCH * DEC_H) {
        int b = idx / DEC_H, j = idx % DEC_H;
        int half = j >> 1;
        float h = (j & 1) ? hR[b * ENC_H + half] : hF[b * ENC_H + half];
        float c = (j & 1) ? cR[b * ENC_H + half] : cF[b * ENC_H + half];
        attn_cat[(size_t)b * 2 * DEC_H + DEC_H + j] = h;
        catA[(size_t)b * KCAT + DEC_IN + j] = h;
        cdec[idx] = c;
    } else {
        int i = idx - BATCH * DEC_H;
        if (i >= BATCH * EMB) return;
        int b = i / EMB, e = i % EMB;
        catA[(size_t)b * KCAT + DEC_H + e] = DEMB[(size_t)trg[b] * EMB + e];
    }
}

__global__ __launch_bounds__(256)
void log_softmax_rows(float* __restrict__ X, int V)
{
    int row = blockIdx.x;
    float* x = X + (size_t)row * V;
    int tid = threadIdx.x;
    __shared__ float redm[4], reds[4];
    float m = -1e30f;
    for (int i = tid; i < V; i += 256) m = fmaxf(m, x[i]);
    for (int off = 32; off; off >>= 1) m = fmaxf(m, __shfl_xor(m, off));
    if ((tid & 63) == 0) redm[tid >> 6] = m;
    __syncthreads();
    m = fmaxf(fmaxf(redm[0], redm[1]), fmaxf(redm[2], redm[3]));
    float s = 0.f;
    for (int i = tid; i < V; i += 256) s += expf(x[i] - m);
    for (int off = 32; off; off >>= 1) s += __shfl_xor(s, off);
    if ((tid & 63) == 0) reds[tid >> 6] = s;
    __syncthreads();
    s = reds[0] + reds[1] + reds[2] + reds[3];
    float lg = m + logf(s);
    for (int i = tid; i < V; i += 256) x[i] -= lg;
}

// ---------------- big GEMM launchers ----------------
static void launch_gemm_big_bias(const float* A, const float* W, const float* bias, float* C,
                                 int M, int N, int K, int ldc, hipStream_t s)
{
    dim3 g(cdiv(N, 128), cdiv(M, 128), 1);
    gemm_bt<128, 128, 16, 8, 8, true><<<g, 256, 0, s>>>(A, W, bias, C, M, N, K, ldc);
}
static void launch_gemm_big(const float* A, const float* W, float* C,
                            int M, int N, int K, int ldc, hipStream_t s)
{
    dim3 g(cdiv(N, 128), cdiv(M, 128), 1);
    gemm_bt<128, 128, 16, 8, 8, false><<<g, 256, 0, s>>>(A, W, nullptr, C, M, N, K, ldc);
}

extern "C" void kernel_launch(void* const* d_in, const int* in_sizes, int n_in,
                              void* d_out, int out_size, void* d_ws, size_t ws_size,
                              hipStream_t stream)
{
    const int*   src   = (const int*)d_in[0];
    const int*   trg   = (const int*)d_in[1];
    const float* EEMBp = (const float*)d_in[2];
    const float* eWihF = (const float*)d_in[3];
    const float* eWhhF = (const float*)d_in[4];
    const float* ebF   = (const float*)d_in[5];
    const float* eWihR = (const float*)d_in[6];
    const float* eWhhR = (const float*)d_in[7];
    const float* ebR   = (const float*)d_in[8];
    const float* aWi   = (const float*)d_in[9];
    const float* aWo   = (const float*)d_in[10];
    const float* dWih  = (const float*)d_in[11];
    const float* dWhh  = (const float*)d_in[12];
    const float* db    = (const float*)d_in[13];
    const float* DEMBp = (const float*)d_in[14];
    const float* gW    = (const float*)d_in[15];
    const float* gb    = (const float*)d_in[16];
    float* out = (float*)d_out;
    float* ws  = (float*)d_ws;

    size_t off = 0;
    auto alloc = [&](size_t n) { float* p = ws + off; off += n; return p; };

    float* Gf      = alloc((size_t)S_LEN * BATCH * 4 * ENC_H);   // gWb alias after enc
    float* Gr      = alloc((size_t)S_LEN * BATCH * 4 * ENC_H);   // encP alias after enc
    float* emb_src = alloc((size_t)S_LEN * BATCH * EMB);
    float* enc_out = alloc((size_t)S_LEN * BATCH * DEC_H);
    float* hF2     = alloc((size_t)2 * BATCH * ENC_H);
    float* hR2     = alloc((size_t)2 * BATCH * ENC_H);
    float* cF      = alloc(BATCH * ENC_H);
    float* cR      = alloc(BATCH * ENC_H);
    float* wihF_i  = alloc((size_t)4 * ENC_H * EMB);
    float* wihR_i  = alloc((size_t)4 * ENC_H * EMB);
    float* whhF_i  = alloc((size_t)4 * ENC_H * ENC_H);
    float* whhR_i  = alloc((size_t)4 * ENC_H * ENC_H);
    float* ebF_i   = alloc(4 * ENC_H);
    float* ebR_i   = alloc(4 * ENC_H);
    float* wcat_i  = alloc((size_t)4 * DEC_H * KCAT);
    float* db_i    = alloc(4 * DEC_H);
    float* aWiT    = alloc((size_t)DEC_H * DEC_H);
    float* cdec    = alloc(BATCH * DEC_H);
    float* attn_cat= alloc((size_t)BATCH * 2 * DEC_H);           // [s_tilde | h]
    float* catA    = alloc((size_t)BATCH * KCAT);                // [c_t | emb | h]
    float* gpart   = alloc((size_t)BATCH * GN);                  // gates partial (emb|h)
    __hip_bfloat16* H_bf = (__hip_bfloat16*)alloc((size_t)(T_LEN - 1) * BATCH * DEC_H / 2);
    unsigned* barcnt = (unsigned*)alloc(16);
    __hip_bfloat16* gWb = (__hip_bfloat16*)Gf;                   // alias
    float* encP = Gr;                                            // alias

    const int HS = BATCH * ENC_H;

    // ---- zero: output slice 0, h/c states (contiguous 6*HS), barrier counters ----
    zero_f32<<<cdiv(BATCH * TRG_V, 256), 256, 0, stream>>>(out, (size_t)BATCH * TRG_V);
    zero_f32<<<cdiv(6 * HS, 256), 256, 0, stream>>>(hF2, (size_t)6 * HS);
    zero_f32<<<1, 16, 0, stream>>>((float*)barcnt, 16);

    // ---- source embeddings ----
    gather_rows<<<cdiv(S_LEN * BATCH * EMB, 256), 256, 0, stream>>>(src, EEMBp, emb_src, S_LEN * BATCH, EMB);

    // ---- interleaved weights/biases + aWi transpose ----
    interleave_rows<<<cdiv(4 * ENC_H * EMB, 256), 256, 0, stream>>>(eWihF, wihF_i, ENC_H, EMB);
    interleave_rows<<<cdiv(4 * ENC_H * EMB, 256), 256, 0, stream>>>(eWihR, wihR_i, ENC_H, EMB);
    interleave_rows<<<cdiv(4 * ENC_H * ENC_H, 256), 256, 0, stream>>>(eWhhF, whhF_i, ENC_H, ENC_H);
    interleave_rows<<<cdiv(4 * ENC_H * ENC_H, 256), 256, 0, stream>>>(eWhhR, whhR_i, ENC_H, ENC_H);
    interleave_vec<<<cdiv(4 * ENC_H, 256), 256, 0, stream>>>(ebF, ebF_i, ENC_H);
    interleave_vec<<<cdiv(4 * ENC_H, 256), 256, 0, stream>>>(ebR, ebR_i, ENC_H);
    build_wcat_int<<<cdiv(4 * DEC_H * KCAT, 256), 256, 0, stream>>>(dWih, dWhh, wcat_i);
    interleave_vec<<<cdiv(4 * DEC_H, 256), 256, 0, stream>>>(db, db_i, DEC_H);
    transpose_sq<<<cdiv(DEC_H * DEC_H, 256), 256, 0, stream>>>(aWi, aWiT, DEC_H);

    // ---- encoder input GEMMs ----
    launch_gemm_big_bias(emb_src, wihF_i, ebF_i, Gf, S_LEN * BATCH, 4 * ENC_H, EMB, 4 * ENC_H, stream);
    launch_gemm_big_bias(emb_src, wihR_i, ebR_i, Gr, S_LEN * BATCH, 4 * ENC_H, EMB, 4 * ENC_H, stream);

    // ---- persistent encoder ----
    enc_persistent<<<256, 256, 0, stream>>>(Gf, Gr, whhF_i, whhR_i, hF2, hR2, cF, cR,
                                            enc_out, &barcnt[0]);

    // ---- hoisted: encP = enc_out @ aWi ----
    launch_gemm_big(enc_out, aWiT, encP, S_LEN * BATCH, DEC_H, DEC_H, DEC_H, stream);

    // ---- cast generator weights into Gf's dead space ----
    cast_f32_bf16<<<cdiv((int)((size_t)TRG_V * DEC_H / 4), 256), 256, 0, stream>>>(gW, gWb, (size_t)TRG_V * DEC_H);

    // ---- decoder init ----
    dec_init2<<<cdiv(BATCH * DEC_H + BATCH * EMB, 256), 256, 0, stream>>>(
        hF2, cF, hR2, cR, trg, DEMBp, attn_cat, catA, cdec);

    // ---- persistent decoder ----
    dec_persistent<<<256, 256, 0, stream>>>(encP, enc_out, trg, DEMBp, aWo, wcat_i, db_i,
                                            attn_cat, catA, cdec, gpart, H_bf, &barcnt[1]);

    // ---- generator: MFMA bf16 GEMM ----
    {
        dim3 g(cdiv(TRG_V, 128), cdiv((T_LEN - 1) * BATCH, 128), 1);
        gemm_mfma_bf16<<<g, 256, 0, stream>>>(H_bf, gWb, gb, out + (size_t)BATCH * TRG_V,
                                              (T_LEN - 1) * BATCH, TRG_V, DEC_H, TRG_V);
    }

    // ---- in-place log_softmax over vocab ----
    log_softmax_rows<<<(T_LEN - 1) * BATCH, 256, 0, stream>>>(out + (size_t)BATCH * TRG_V, TRG_V);
}

// Round 13
// 12520.605 us; speedup vs baseline: 1.1318x; 1.1318x over previous
//
#include <hip/hip_runtime.h>
#include <hip/hip_bf16.h>

#define S_LEN 50
#define T_LEN 50
#define BATCH 128
#define EMB 300
#define ENC_H 512
#define DEC_H 1024
#define TRG_V 23262
#define DEC_IN (DEC_H + EMB)      // 1324
#define KCAT (DEC_IN + DEC_H)     // 2348
#define GN (4 * DEC_H)            // 4096

static inline int cdiv(int a, int b) { return (a + b - 1) / b; }

__device__ __forceinline__ float sigm(float x) { return 1.f / (1.f + expf(-x)); }

typedef __attribute__((ext_vector_type(8))) short bf16x8;
typedef __attribute__((ext_vector_type(4))) float f32x4;

__device__ __forceinline__ void gload_lds16(const void* g, void* l) {
    __builtin_amdgcn_global_load_lds((const __attribute__((address_space(1))) int*)g,
                                     (__attribute__((address_space(3))) int*)l, 16, 0, 0);
}

// ---------------- LLC-coherent access helpers (agent-scope relaxed atomics) ----
// These bypass the non-coherent per-XCD caches and are served at the LLC, so
// cross-block communication needs NO fences (and thus no L2 invalidation).
__device__ __forceinline__ float cload1(const float* p) {
    return __hip_atomic_load(p, __ATOMIC_RELAXED, __HIP_MEMORY_SCOPE_AGENT);
}
__device__ __forceinline__ float2 cload2(const float* p) {
    unsigned long long u = __hip_atomic_load((const unsigned long long*)p,
                                             __ATOMIC_RELAXED, __HIP_MEMORY_SCOPE_AGENT);
    union U { unsigned long long u; float2 f; } c; c.u = u; return c.f;
}
__device__ __forceinline__ float4 cload4(const float* p) {
    float2 a = cload2(p), b = cload2(p + 2);
    return make_float4(a.x, a.y, b.x, b.y);
}
__device__ __forceinline__ void cstore1(float* p, float v) {
    __hip_atomic_store(p, v, __ATOMIC_RELAXED, __HIP_MEMORY_SCOPE_AGENT);
}
__device__ __forceinline__ void cstore2(float* p, float2 v) {
    union U { unsigned long long u; float2 f; } c; c.f = v;
    __hip_atomic_store((unsigned long long*)p, c.u, __ATOMIC_RELAXED, __HIP_MEMORY_SCOPE_AGENT);
}
__device__ __forceinline__ void cstore4(float* p, float4 v) {
    cstore2(p, make_float2(v.x, v.y)); cstore2(p + 2, make_float2(v.z, v.w));
}

// ---------------- grid barrier: fence-free (communication is LLC-coherent) ----
// __syncthreads drains each wave's vmcnt before s_barrier, so all this block's
// (coherent) stores are globally visible before the ticket increment.
__device__ __forceinline__ void gbar(unsigned* cnt, unsigned target) {
    __syncthreads();
    if (threadIdx.x == 0) {
        atomicAdd(cnt, 1u);
        while (atomicAdd(cnt, 0u) < target)
            __builtin_amdgcn_s_sleep(32);
    }
    __syncthreads();
}

// ---------------- MFMA bf16 GEMM (generator): C = A @ W^T + bias ----------------
__global__ __launch_bounds__(256)
void gemm_mfma_bf16(const __hip_bfloat16* __restrict__ A, const __hip_bfloat16* __restrict__ W,
                    const float* __restrict__ bias, float* __restrict__ C,
                    int M, int N, int K, int ldc)
{
    __shared__ short As[128 * 32];
    __shared__ short Bs[128 * 32];
    const int tid  = threadIdx.x;
    const int wave = tid >> 6;
    const int lane = tid & 63;
    const int m0 = blockIdx.y * 128;
    const int n0 = blockIdx.x * 128;
    const int wr = wave >> 1, wc = wave & 1;

    const int srow = lane >> 2;
    const int kgrp = lane & 3;
    const int arow0 = 32 * wave;

    f32x4 acc[4][4] = {};

    for (int k0 = 0; k0 < K; k0 += 32) {
#pragma unroll
        for (int c = 0; c < 2; c++) {
            int row = arow0 + 16 * c + srow;
            gload_lds16(A + (size_t)(m0 + row) * K + k0 + kgrp * 8,
                        &As[(arow0 + 16 * c) * 32]);
        }
#pragma unroll
        for (int c = 0; c < 2; c++) {
            int row = arow0 + 16 * c + srow;
            int gr = n0 + row; if (gr > N - 1) gr = N - 1;
            gload_lds16(W + (size_t)gr * K + k0 + kgrp * 8,
                        &Bs[(arow0 + 16 * c) * 32]);
        }
        __syncthreads();

        bf16x8 a[4], b[4];
#pragma unroll
        for (int mi = 0; mi < 4; mi++)
            a[mi] = *(const bf16x8*)&As[(wr * 64 + mi * 16 + (lane & 15)) * 32 + (lane >> 4) * 8];
#pragma unroll
        for (int ni = 0; ni < 4; ni++)
            b[ni] = *(const bf16x8*)&Bs[(wc * 64 + ni * 16 + (lane & 15)) * 32 + (lane >> 4) * 8];
#pragma unroll
        for (int mi = 0; mi < 4; mi++)
#pragma unroll
            for (int ni = 0; ni < 4; ni++)
                acc[mi][ni] = __builtin_amdgcn_mfma_f32_16x16x32_bf16(a[mi], b[ni], acc[mi][ni], 0, 0, 0);
        __syncthreads();
    }

#pragma unroll
    for (int mi = 0; mi < 4; mi++)
#pragma unroll
        for (int ni = 0; ni < 4; ni++) {
            int col = n0 + wc * 64 + ni * 16 + (lane & 15);
            if (col >= N) continue;
            float bv = bias[col];
#pragma unroll
            for (int r = 0; r < 4; r++) {
                int row = m0 + wr * 64 + mi * 16 + (lane >> 4) * 4 + r;
                C[(size_t)row * ldc + col] = acc[mi][ni][r] + bv;
            }
        }
}

__global__ void cast_f32_bf16(const float* __restrict__ in, __hip_bfloat16* __restrict__ out, size_t n)
{
    size_t i = ((size_t)blockIdx.x * blockDim.x + threadIdx.x) * 4;
    if (i + 3 < n) {
        float4 v = *(const float4*)(in + i);
        out[i + 0] = __float2bfloat16(v.x);
        out[i + 1] = __float2bfloat16(v.y);
        out[i + 2] = __float2bfloat16(v.z);
        out[i + 3] = __float2bfloat16(v.w);
    } else {
        for (; i < n; i++) out[i] = __float2bfloat16(in[i]);
    }
}

// ---------------- generic fp32 GEMM (big, 128x128 tiles): C = A @ W^T (+bias) ----------------
template<int BM, int BN, int BK, int TM, int TN, bool HAS_BIAS>
__global__ __launch_bounds__((BM / TM) * (BN / TN))
void gemm_bt(const float* __restrict__ A, const float* __restrict__ W,
             const float* __restrict__ bias, float* __restrict__ C,
             int M, int N, int K, int ldc)
{
    constexpr int NT  = (BM / TM) * (BN / TN);
    constexpr int NGA = TM / 4;
    constexpr int NGB = TN / 4;
    constexpr int GS  = (BN / TN) * 4;
    constexpr int LPA = BM * BK / 4 / NT;
    constexpr int LPB = BN * BK / 4 / NT;

    __shared__ float As[BK][BM + 4];
    __shared__ float Bs[BK][BN + 4];

    const int tid = threadIdx.x;
    const int tx = tid % (BN / TN);
    const int ty = tid / (BN / TN);
    const int m0 = blockIdx.y * BM;
    const int n0 = blockIdx.x * BN;

    float acc[TM][TN];
#pragma unroll
    for (int i = 0; i < TM; i++)
#pragma unroll
        for (int j = 0; j < TN; j++) acc[i][j] = 0.f;

    for (int k0 = 0; k0 < K; k0 += BK) {
#pragma unroll
        for (int e = 0; e < LPA; e++) {
            int idx = tid + e * NT;
            int r = idx / (BK / 4);
            int c4 = idx % (BK / 4);
            int row = m0 + r; if (row > M - 1) row = M - 1;
            int kk = k0 + c4 * 4;
            float4 v;
            if (kk + 3 < K) {
                v = *(const float4*)(A + (size_t)row * K + kk);
            } else {
                v.x = (kk + 0 < K) ? A[(size_t)row * K + kk + 0] : 0.f;
                v.y = (kk + 1 < K) ? A[(size_t)row * K + kk + 1] : 0.f;
                v.z = (kk + 2 < K) ? A[(size_t)row * K + kk + 2] : 0.f;
                v.w = (kk + 3 < K) ? A[(size_t)row * K + kk + 3] : 0.f;
            }
            As[c4 * 4 + 0][r] = v.x; As[c4 * 4 + 1][r] = v.y;
            As[c4 * 4 + 2][r] = v.z; As[c4 * 4 + 3][r] = v.w;
        }
#pragma unroll
        for (int e = 0; e < LPB; e++) {
            int idx = tid + e * NT;
            int r = idx / (BK / 4);
            int c4 = idx % (BK / 4);
            int row = n0 + r; if (row > N - 1) row = N - 1;
            int kk = k0 + c4 * 4;
            float4 v;
            if (kk + 3 < K) {
                v = *(const float4*)(W + (size_t)row * K + kk);
            } else {
                v.x = (kk + 0 < K) ? W[(size_t)row * K + kk + 0] : 0.f;
                v.y = (kk + 1 < K) ? W[(size_t)row * K + kk + 1] : 0.f;
                v.z = (kk + 2 < K) ? W[(size_t)row * K + kk + 2] : 0.f;
                v.w = (kk + 3 < K) ? W[(size_t)row * K + kk + 3] : 0.f;
            }
            Bs[c4 * 4 + 0][r] = v.x; Bs[c4 * 4 + 1][r] = v.y;
            Bs[c4 * 4 + 2][r] = v.z; Bs[c4 * 4 + 3][r] = v.w;
        }
        __syncthreads();
#pragma unroll
        for (int kk = 0; kk < BK; kk++) {
            float a[TM], b[TN];
#pragma unroll
            for (int g = 0; g < NGA; g++) {
                float4 v = *(const float4*)(&As[kk][ty * TM + g * 4]);
                a[g * 4 + 0] = v.x; a[g * 4 + 1] = v.y; a[g * 4 + 2] = v.z; a[g * 4 + 3] = v.w;
            }
#pragma unroll
            for (int g = 0; g < NGB; g++) {
                float4 v = *(const float4*)(&Bs[kk][tx * 4 + g * GS]);
                b[g * 4 + 0] = v.x; b[g * 4 + 1] = v.y; b[g * 4 + 2] = v.z; b[g * 4 + 3] = v.w;
            }
#pragma unroll
            for (int i = 0; i < TM; i++)
#pragma unroll
                for (int j = 0; j < TN; j++)
                    acc[i][j] = fmaf(a[i], b[j], acc[i][j]);
        }
        __syncthreads();
    }

#pragma unroll
    for (int i = 0; i < TM; i++) {
        int row = m0 + ty * TM + i;
        if (row >= M) continue;
#pragma unroll
        for (int g = 0; g < NGB; g++) {
            int colb = n0 + tx * 4 + g * GS;
#pragma unroll
            for (int j = 0; j < 4; j++) {
                int cc = colb + j;
                if (cc >= N) continue;
                float v = acc[i][g * 4 + j];
                if (HAS_BIAS) v += bias[cc];
                C[(size_t)row * ldc + cc] = v;
            }
        }
    }
}

// ---------------- 32x64-tile fp32 GEMM core (depth-2 prefetch, coherent A) ----
__device__ __forceinline__ float4 g4k(const float* base, int kk, int K) {
    float4 v = make_float4(0.f, 0.f, 0.f, 0.f);
    if (kk + 3 < K) v = *(const float4*)(base + kk);
    else {
        if (kk     < K) v.x = base[kk];
        if (kk + 1 < K) v.y = base[kk + 1];
        if (kk + 2 < K) v.z = base[kk + 2];
    }
    return v;
}
__device__ __forceinline__ float4 g4kc(const float* base, int kk, int K) {
    float4 v = make_float4(0.f, 0.f, 0.f, 0.f);
    if (kk + 3 < K) v = cload4(base + kk);
    else {
        if (kk     < K) v.x = cload1(base + kk);
        if (kk + 1 < K) v.y = cload1(base + kk + 1);
        if (kk + 2 < K) v.z = cload1(base + kk + 2);
    }
    return v;
}

// A is read coherently (cross-block data); W (weights) via ordinary cached loads.
__device__ __forceinline__ void tile_core(
    float (&As)[2][32][36], float (&Bs)[2][32][68],
    const float* __restrict__ A, int lda,
    const float* __restrict__ W, int ldw, int K,
    int m0, int n0, float (&acc)[2][4])
{
    const int tid = threadIdx.x;
    const int tx = tid & 15, ty = tid >> 4;
    const int ar = tid >> 3, ac4 = tid & 7;
    const float* abase = A + (size_t)(m0 + ar) * lda;
    const float* bb0   = W + (size_t)(n0 + ar) * ldw;
    const float* bb1   = bb0 + (size_t)32 * ldw;

    acc[0][0]=acc[0][1]=acc[0][2]=acc[0][3]=0.f;
    acc[1][0]=acc[1][1]=acc[1][2]=acc[1][3]=0.f;
    const int NIT = (K + 31) / 32;

    float4 pa0, pb00, pb10;   // slot 0
    float4 pa1, pb01, pb11;   // slot 1

    auto LOAD = [&](int itx, float4& qa, float4& qb0, float4& qb1) {
        int k0 = itx * 32, kk = k0 + ac4 * 4;
        if (k0 + 32 <= K) {
            qa = cload4(abase + kk); qb0 = *(const float4*)(bb0 + kk); qb1 = *(const float4*)(bb1 + kk);
        } else {
            qa = g4kc(abase, kk, K); qb0 = g4k(bb0, kk, K); qb1 = g4k(bb1, kk, K);
        }
    };
    auto SLDS = [&](int nb, const float4& qa, const float4& qb0, const float4& qb1) {
        *(float4*)&As[nb][ar][ac4 * 4] = qa;
        Bs[nb][ac4*4+0][ar]    = qb0.x; Bs[nb][ac4*4+1][ar]    = qb0.y;
        Bs[nb][ac4*4+2][ar]    = qb0.z; Bs[nb][ac4*4+3][ar]    = qb0.w;
        Bs[nb][ac4*4+0][ar+32] = qb1.x; Bs[nb][ac4*4+1][ar+32] = qb1.y;
        Bs[nb][ac4*4+2][ar+32] = qb1.z; Bs[nb][ac4*4+3][ar+32] = qb1.w;
    };
    auto COMP = [&](int c) {
#pragma unroll
        for (int k4 = 0; k4 < 8; ++k4) {
            float4 a0 = *(const float4*)&As[c][ty*2+0][k4*4];
            float4 a1 = *(const float4*)&As[c][ty*2+1][k4*4];
            float4 b0 = *(const float4*)&Bs[c][k4*4+0][tx*4];
            float4 b1 = *(const float4*)&Bs[c][k4*4+1][tx*4];
            float4 b2 = *(const float4*)&Bs[c][k4*4+2][tx*4];
            float4 b3 = *(const float4*)&Bs[c][k4*4+3][tx*4];
            float av0[4] = {a0.x, a0.y, a0.z, a0.w};
            float av1[4] = {a1.x, a1.y, a1.z, a1.w};
            float4 bq[4] = {b0, b1, b2, b3};
#pragma unroll
            for (int q = 0; q < 4; q++) {
                acc[0][0] = fmaf(av0[q], bq[q].x, acc[0][0]);
                acc[0][1] = fmaf(av0[q], bq[q].y, acc[0][1]);
                acc[0][2] = fmaf(av0[q], bq[q].z, acc[0][2]);
                acc[0][3] = fmaf(av0[q], bq[q].w, acc[0][3]);
                acc[1][0] = fmaf(av1[q], bq[q].x, acc[1][0]);
                acc[1][1] = fmaf(av1[q], bq[q].y, acc[1][1]);
                acc[1][2] = fmaf(av1[q], bq[q].z, acc[1][2]);
                acc[1][3] = fmaf(av1[q], bq[q].w, acc[1][3]);
            }
        }
    };

    LOAD(0, pa0, pb00, pb10);
    if (NIT > 1) LOAD(1, pa1, pb01, pb11);
    SLDS(0, pa0, pb00, pb10);
    __syncthreads();

    int cur = 0;
    int it = 0;
    while (it < NIT) {
        // even iteration: prefetch -> slot0, LDS-store <- slot1
        if (it + 2 < NIT) LOAD(it + 2, pa0, pb00, pb10);
        COMP(cur);
        if (it + 1 < NIT) SLDS(cur ^ 1, pa1, pb01, pb11);
        __syncthreads();
        cur ^= 1; ++it;
        if (it >= NIT) break;
        // odd iteration: prefetch -> slot1, LDS-store <- slot0
        if (it + 2 < NIT) LOAD(it + 2, pa1, pb01, pb11);
        COMP(cur);
        if (it + 1 < NIT) SLDS(cur ^ 1, pa0, pb00, pb10);
        __syncthreads();
        cur ^= 1; ++it;
    }
}

// ---------------- attention body (one block per batch row; s_tilde only) ----------------
__device__ __forceinline__ void attn_body(
    int b, float* hv, float* sc,
    const float* __restrict__ encP, const float* __restrict__ enc_out,
    float* __restrict__ attn_cat)
{
    const int tid = threadIdx.x;
    for (int d = tid; d < DEC_H; d += 256) hv[d] = cload1(&attn_cat[(size_t)b * 2 * DEC_H + DEC_H + d]);
    __syncthreads();
    int wave = tid >> 6, lane = tid & 63;
    for (int s = wave; s < S_LEN; s += 4) {
        const float* e = encP + ((size_t)s * BATCH + b) * DEC_H;
        float p = 0.f;
        for (int d = lane; d < DEC_H; d += 64) p = fmaf(e[d], hv[d], p);
        for (int off = 32; off; off >>= 1) p += __shfl_down(p, off);
        if (lane == 0) sc[s] = p;
    }
    __syncthreads();
    if (tid < 64) {
        float x = (tid < S_LEN) ? sc[tid] : -1e30f;
        float m = x;
        for (int off = 32; off; off >>= 1) m = fmaxf(m, __shfl_xor(m, off));
        float ex = (tid < S_LEN) ? expf(x - m) : 0.f;
        float ssum = ex;
        for (int off = 32; off; off >>= 1) ssum += __shfl_xor(ssum, off);
        if (tid < S_LEN) sc[tid] = ex / ssum;
    }
    __syncthreads();
    for (int d = tid; d < DEC_H; d += 256) {
        float a = 0.f;
#pragma unroll 5
        for (int s = 0; s < S_LEN; s++)
            a = fmaf(sc[s], enc_out[((size_t)s * BATCH + b) * DEC_H + d], a);
        cstore1(&attn_cat[(size_t)b * 2 * DEC_H + d], a);
    }
}

// ---------------- persistent encoder: 50 steps, 1 barrier/step ----------------
__global__ __launch_bounds__(256)
void enc_persistent(const float* __restrict__ Gf, const float* __restrict__ Gr,
                    const float* __restrict__ whhF, const float* __restrict__ whhR,
                    float* __restrict__ hF2, float* __restrict__ hR2,
                    float* __restrict__ cF, float* __restrict__ cR,
                    float* __restrict__ enc_out, unsigned* __restrict__ barcnt)
{
    __shared__ struct { float As[2][32][36]; float Bs[2][32][68]; } sm;
    const int blk = blockIdx.x;
    const int tid = threadIdx.x;
    const int tx = tid & 15, ty = tid >> 4;
    const int dir = blk >> 7;
    const int id  = blk & 127;
    const int m0 = (id >> 5) * 32;
    const int n0 = (id & 31) * 64;
    const float* W  = dir ? whhR : whhF;
    float* cst      = dir ? cR : cF;
    float* hbase    = dir ? hR2 : hF2;
    const float* G  = dir ? Gr : Gf;
    const int HS = BATCH * ENC_H;
    unsigned epoch = 0;
    float acc[2][4];

    for (int t = 0; t < S_LEN; ++t) {
        const float* h_in = hbase + (size_t)(t & 1) * HS;
        float* h_out      = hbase + (size_t)((t + 1) & 1) * HS;
        int s_g = dir ? (S_LEN - 1 - t) : t;
        const float* D = G + (size_t)s_g * BATCH * 4 * ENC_H;

        tile_core(sm.As, sm.Bs, h_in, ENC_H, W, ENC_H, ENC_H, m0, n0, acc);

        int cb = n0 + tx * 4, j = cb >> 2;
#pragma unroll
        for (int i = 0; i < 2; i++) {
            int b = m0 + ty * 2 + i;
            float4 d4 = *(const float4*)(D + (size_t)b * 4 * ENC_H + cb);
            float gi = acc[i][0] + d4.x, gf = acc[i][1] + d4.y;
            float gg = acc[i][2] + d4.z, go = acc[i][3] + d4.w;
            float c2 = sigm(gf) * cst[b * ENC_H + j] + sigm(gi) * tanhf(gg);
            float h2 = sigm(go) * tanhf(c2);
            cst[b * ENC_H + j] = c2;                 // same-block state
            cstore1(&h_out[b * ENC_H + j], h2);      // cross-block
            enc_out[((size_t)s_g * BATCH + b) * DEC_H + dir * ENC_H + j] = h2;  // next kernels
        }
        if (t < S_LEN - 1) gbar(barcnt, 256u * (++epoch));
    }
}

// ---------------- persistent decoder: 49 steps x 3 balanced phases ----------------
__global__ __launch_bounds__(256)
void dec_persistent(const float* __restrict__ encP, const float* __restrict__ enc_out,
                    const int* __restrict__ trg, const float* __restrict__ DEMB,
                    const float* __restrict__ aWo, const float* __restrict__ wcat,
                    const float* __restrict__ db_i,
                    float* __restrict__ attn_cat, float* __restrict__ catA,
                    float* __restrict__ cdec, float* __restrict__ gpart,
                    __hip_bfloat16* __restrict__ H_bf, unsigned* __restrict__ barcnt)
{
    __shared__ union {
        struct { float hv[DEC_H]; float sc[S_LEN]; } a;
        struct { float As[2][32][36]; float Bs[2][32][68]; } g;
    } sm;
    const int blk = blockIdx.x;
    const int tid = threadIdx.x;
    const int tx = tid & 15, ty = tid >> 4;
    unsigned epoch = 0;
    float acc[2][4];

    for (int t = 0; t < T_LEN - 1; ++t) {
        // ---- Phase A: attn (0-127) || aWo_h partial (128-191) || gates-hemb tiles 0-63 (192-255)
        if (blk < 128) {
            attn_body(blk, sm.a.hv, sm.a.sc, encP, enc_out, attn_cat);
        } else if (blk < 192) {
            int id = blk - 128;
            int m0 = (id >> 4) * 32, n0 = (id & 15) * 64;
            tile_core(sm.g.As, sm.g.Bs, attn_cat + DEC_H, 2 * DEC_H,
                      aWo + DEC_H, 2 * DEC_H, DEC_H, m0, n0, acc);
            int cb = n0 + tx * 4;
#pragma unroll
            for (int i = 0; i < 2; i++) {
                int row = m0 + ty * 2 + i;
                cstore4(catA + (size_t)row * KCAT + cb,
                        make_float4(acc[i][0], acc[i][1], acc[i][2], acc[i][3]));
            }
        } else {
            int tau = blk - 192;                    // tiles 0..63
            int m0 = (tau >> 6) * 32, n0 = (tau & 63) * 64;
            tile_core(sm.g.As, sm.g.Bs, catA + DEC_H, KCAT,
                      wcat + DEC_H, KCAT, KCAT - DEC_H, m0, n0, acc);
            int cb = n0 + tx * 4;
#pragma unroll
            for (int i = 0; i < 2; i++) {
                int row = m0 + ty * 2 + i;
                cstore4(gpart + (size_t)row * GN + cb,
                        make_float4(acc[i][0], acc[i][1], acc[i][2], acc[i][3]));
            }
        }
        gbar(barcnt, 256u * (++epoch));

        // ---- Phase B: aWo_s~ + add + tanh (0-63) || gates-hemb tiles 64-255 (64-255)
        if (blk < 64) {
            int m0 = (blk >> 4) * 32, n0 = (blk & 15) * 64;
            tile_core(sm.g.As, sm.g.Bs, attn_cat, 2 * DEC_H, aWo, 2 * DEC_H, DEC_H, m0, n0, acc);
            int cb = n0 + tx * 4;
#pragma unroll
            for (int i = 0; i < 2; i++) {
                int row = m0 + ty * 2 + i;
                float* dst = catA + (size_t)row * KCAT + cb;
                float4 prev = cload4(dst);
                cstore4(dst, make_float4(tanhf(acc[i][0] + prev.x), tanhf(acc[i][1] + prev.y),
                                         tanhf(acc[i][2] + prev.z), tanhf(acc[i][3] + prev.w)));
            }
        } else {
            int tau = blk;                          // tiles 64..255
            int m0 = (tau >> 6) * 32, n0 = (tau & 63) * 64;
            tile_core(sm.g.As, sm.g.Bs, catA + DEC_H, KCAT,
                      wcat + DEC_H, KCAT, KCAT - DEC_H, m0, n0, acc);
            int cb = n0 + tx * 4;
#pragma unroll
            for (int i = 0; i < 2; i++) {
                int row = m0 + ty * 2 + i;
                cstore4(gpart + (size_t)row * GN + cb,
                        make_float4(acc[i][0], acc[i][1], acc[i][2], acc[i][3]));
            }
        }
        gbar(barcnt, 256u * (++epoch));

        // ---- Phase C: gates-ct (K=1024) + gpart + bias + LSTM epilogue (all 256)
        {
            int m0 = (blk >> 6) * 32, n0 = (blk & 63) * 64;
            tile_core(sm.g.As, sm.g.Bs, catA, KCAT, wcat, KCAT, DEC_H, m0, n0, acc);
            int cb = n0 + tx * 4, j = cb >> 2;
            float4 bz = *(const float4*)(db_i + cb);
#pragma unroll
            for (int i = 0; i < 2; i++) {
                int b = m0 + ty * 2 + i;
                float4 gp = cload4(gpart + (size_t)b * GN + cb);
                float gi = acc[i][0] + gp.x + bz.x, gf = acc[i][1] + gp.y + bz.y;
                float gg = acc[i][2] + gp.z + bz.z, go = acc[i][3] + gp.w + bz.w;
                float c2 = sigm(gf) * cdec[b * DEC_H + j] + sigm(gi) * tanhf(gg);
                float h2 = sigm(go) * tanhf(c2);
                cdec[b * DEC_H + j] = c2;            // same-block state
                H_bf[(size_t)t * BATCH * DEC_H + b * DEC_H + j] = __float2bfloat16(h2);  // next kernel
                cstore1(&attn_cat[(size_t)b * 2 * DEC_H + DEC_H + j], h2);
                cstore1(&catA[(size_t)b * KCAT + DEC_IN + j], h2);
            }
            // stage next step's target embedding (blocks with n0==0; rows m0..m0+31)
            if ((blk & 63) == 0 && t + 1 < T_LEN - 1) {
                for (int idx = tid; idx < 32 * EMB; idx += 256) {
                    int r = m0 + idx / EMB, e = idx % EMB;
                    int idt = trg[(t + 1) * BATCH + r];
                    cstore1(&catA[(size_t)r * KCAT + DEC_H + e], DEMB[(size_t)idt * EMB + e]);
                }
            }
        }
        if (t < T_LEN - 2) gbar(barcnt, 256u * (++epoch));
    }
}

// ---------------- small kernels ----------------
__global__ void zero_f32(float* p, size_t n) {
    size_t i = (size_t)blockIdx.x * blockDim.x + threadIdx.x;
    if (i < n) p[i] = 0.f;
}

__global__ void gather_rows(const int* __restrict__ ids, const float* __restrict__ E,
                            float* __restrict__ out, int nrows, int width)
{
    size_t i = (size_t)blockIdx.x * blockDim.x + threadIdx.x;
    size_t total = (size_t)nrows * width;
    if (i >= total) return;
    int r = (int)(i / width);
    int e = (int)(i % width);
    out[i] = E[(size_t)ids[r] * width + e];
}

__global__ void interleave_rows(const float* __restrict__ src, float* __restrict__ dst,
                                int units, int kdim)
{
    size_t i = (size_t)blockIdx.x * blockDim.x + threadIdx.x;
    size_t total = (size_t)4 * units * kdim;
    if (i >= total) return;
    int ir = (int)(i / kdim), k = (int)(i % kdim);
    int gate = ir & 3, j = ir >> 2;
    dst[i] = src[(size_t)(gate * units + j) * kdim + k];
}

__global__ void interleave_vec(const float* __restrict__ src, float* __restrict__ dst, int units)
{
    int i = blockIdx.x * blockDim.x + threadIdx.x;
    if (i >= 4 * units) return;
    int gate = i & 3, j = i >> 2;
    dst[i] = src[gate * units + j];
}

__global__ void build_wcat_int(const float* __restrict__ Wih, const float* __restrict__ Whh,
                               float* __restrict__ dst)
{
    size_t i = (size_t)blockIdx.x * blockDim.x + threadIdx.x;
    if (i >= (size_t)4 * DEC_H * KCAT) return;
    int ir = (int)(i / KCAT), k = (int)(i % KCAT);
    int gate = ir & 3, j = ir >> 2;
    int r = gate * DEC_H + j;
    dst[i] = (k < DEC_IN) ? Wih[(size_t)r * DEC_IN + k] : Whh[(size_t)r * DEC_H + (k - DEC_IN)];
}

__global__ void transpose_sq(const float* __restrict__ src, float* __restrict__ dst, int n)
{
    int i = blockIdx.x * blockDim.x + threadIdx.x;
    if (i >= n * n) return;
    int r = i / n, c = i % n;
    dst[(size_t)r * n + c] = src[(size_t)c * n + r];
}

// decoder init: h0/c0 interleave into attn_cat[h], catA[h], cdec; stage emb t=0
__global__ void dec_init2(const float* __restrict__ hF, const float* __restrict__ cF,
                          const float* __restrict__ hR, const float* __restrict__ cR,
                          const int* __restrict__ trg, const float* __restrict__ DEMB,
                          float* __restrict__ attn_cat, float* __restrict__ catA,
                          float* __restrict__ cdec)
{
    int idx = blockIdx.x * blockDim.x + threadIdx.x;
    if (idx < BATCH * DEC_H) {
        int b = idx / DEC_H, j = idx % DEC_H;
        int half = j >> 1;
        float h = (j & 1) ? hR[b * ENC_H + half] : hF[b * ENC_H + half];
        float c = (j & 1) ? cR[b * ENC_H + half] : cF[b * ENC_H + half];
        attn_cat[(size_t)b * 2 * DEC_H + DEC_H + j] = h;
        catA[(size_t)b * KCAT + DEC_IN + j] = h;
        cdec[idx] = c;
    } else {
        int i = idx - BATCH * DEC_H;
        if (i >= BATCH * EMB) return;
        int b = i / EMB, e = i % EMB;
        catA[(size_t)b * KCAT + DEC_H + e] = DEMB[(size_t)trg[b] * EMB + e];
    }
}

__global__ __launch_bounds__(256)
void log_softmax_rows(float* __restrict__ X, int V)
{
    int row = blockIdx.x;
    float* x = X + (size_t)row * V;
    int tid = threadIdx.x;
    __shared__ float redm[4], reds[4];
    float m = -1e30f;
    for (int i = tid; i < V; i += 256) m = fmaxf(m, x[i]);
    for (int off = 32; off; off >>= 1) m = fmaxf(m, __shfl_xor(m, off));
    if ((tid & 63) == 0) redm[tid >> 6] = m;
    __syncthreads();
    m = fmaxf(fmaxf(redm[0], redm[1]), fmaxf(redm[2], redm[3]));
    float s = 0.f;
    for (int i = tid; i < V; i += 256) s += expf(x[i] - m);
    for (int off = 32; off; off >>= 1) s += __shfl_xor(s, off);
    if ((tid & 63) == 0) reds[tid >> 6] = s;
    __syncthreads();
    s = reds[0] + reds[1] + reds[2] + reds[3];
    float lg = m + logf(s);
    for (int i = tid; i < V; i += 256) x[i] -= lg;
}

// ---------------- big GEMM launchers ----------------
static void launch_gemm_big_bias(const float* A, const float* W, const float* bias, float* C,
                                 int M, int N, int K, int ldc, hipStream_t s)
{
    dim3 g(cdiv(N, 128), cdiv(M, 128), 1);
    gemm_bt<128, 128, 16, 8, 8, true><<<g, 256, 0, s>>>(A, W, bias, C, M, N, K, ldc);
}
static void launch_gemm_big(const float* A, const float* W, float* C,
                            int M, int N, int K, int ldc, hipStream_t s)
{
    dim3 g(cdiv(N, 128), cdiv(M, 128), 1);
    gemm_bt<128, 128, 16, 8, 8, false><<<g, 256, 0, s>>>(A, W, nullptr, C, M, N, K, ldc);
}

extern "C" void kernel_launch(void* const* d_in, const int* in_sizes, int n_in,
                              void* d_out, int out_size, void* d_ws, size_t ws_size,
                              hipStream_t stream)
{
    const int*   src   = (const int*)d_in[0];
    const int*   trg   = (const int*)d_in[1];
    const float* EEMBp = (const float*)d_in[2];
    const float* eWihF = (const float*)d_in[3];
    const float* eWhhF = (const float*)d_in[4];
    const float* ebF   = (const float*)d_in[5];
    const float* eWihR = (const float*)d_in[6];
    const float* eWhhR = (const float*)d_in[7];
    const float* ebR   = (const float*)d_in[8];
    const float* aWi   = (const float*)d_in[9];
    const float* aWo   = (const float*)d_in[10];
    const float* dWih  = (const float*)d_in[11];
    const float* dWhh  = (const float*)d_in[12];
    const float* db    = (const float*)d_in[13];
    const float* DEMBp = (const float*)d_in[14];
    const float* gW    = (const float*)d_in[15];
    const float* gb    = (const float*)d_in[16];
    float* out = (float*)d_out;
    float* ws  = (float*)d_ws;

    size_t off = 0;
    auto alloc = [&](size_t n) { float* p = ws + off; off += n; return p; };

    float* Gf      = alloc((size_t)S_LEN * BATCH * 4 * ENC_H);   // gWb alias after enc
    float* Gr      = alloc((size_t)S_LEN * BATCH * 4 * ENC_H);   // encP alias after enc
    float* emb_src = alloc((size_t)S_LEN * BATCH * EMB);
    float* enc_out = alloc((size_t)S_LEN * BATCH * DEC_H);
    float* hF2     = alloc((size_t)2 * BATCH * ENC_H);
    float* hR2     = alloc((size_t)2 * BATCH * ENC_H);
    float* cF      = alloc(BATCH * ENC_H);
    float* cR      = alloc(BATCH * ENC_H);
    float* wihF_i  = alloc((size_t)4 * ENC_H * EMB);
    float* wihR_i  = alloc((size_t)4 * ENC_H * EMB);
    float* whhF_i  = alloc((size_t)4 * ENC_H * ENC_H);
    float* whhR_i  = alloc((size_t)4 * ENC_H * ENC_H);
    float* ebF_i   = alloc(4 * ENC_H);
    float* ebR_i   = alloc(4 * ENC_H);
    float* wcat_i  = alloc((size_t)4 * DEC_H * KCAT);
    float* db_i    = alloc(4 * DEC_H);
    float* aWiT    = alloc((size_t)DEC_H * DEC_H);
    float* cdec    = alloc(BATCH * DEC_H);
    float* attn_cat= alloc((size_t)BATCH * 2 * DEC_H);           // [s_tilde | h]
    float* catA    = alloc((size_t)BATCH * KCAT);                // [c_t | emb | h]
    float* gpart   = alloc((size_t)BATCH * GN);                  // gates partial (emb|h)
    __hip_bfloat16* H_bf = (__hip_bfloat16*)alloc((size_t)(T_LEN - 1) * BATCH * DEC_H / 2);
    unsigned* barcnt = (unsigned*)alloc(16);
    __hip_bfloat16* gWb = (__hip_bfloat16*)Gf;                   // alias
    float* encP = Gr;                                            // alias

    const int HS = BATCH * ENC_H;

    // ---- zero: output slice 0, h/c states (contiguous 6*HS), barrier counters ----
    zero_f32<<<cdiv(BATCH * TRG_V, 256), 256, 0, stream>>>(out, (size_t)BATCH * TRG_V);
    zero_f32<<<cdiv(6 * HS, 256), 256, 0, stream>>>(hF2, (size_t)6 * HS);
    zero_f32<<<1, 16, 0, stream>>>((float*)barcnt, 16);

    // ---- source embeddings ----
    gather_rows<<<cdiv(S_LEN * BATCH * EMB, 256), 256, 0, stream>>>(src, EEMBp, emb_src, S_LEN * BATCH, EMB);

    // ---- interleaved weights/biases + aWi transpose ----
    interleave_rows<<<cdiv(4 * ENC_H * EMB, 256), 256, 0, stream>>>(eWihF, wihF_i, ENC_H, EMB);
    interleave_rows<<<cdiv(4 * ENC_H * EMB, 256), 256, 0, stream>>>(eWihR, wihR_i, ENC_H, EMB);
    interleave_rows<<<cdiv(4 * ENC_H * ENC_H, 256), 256, 0, stream>>>(eWhhF, whhF_i, ENC_H, ENC_H);
    interleave_rows<<<cdiv(4 * ENC_H * ENC_H, 256), 256, 0, stream>>>(eWhhR, whhR_i, ENC_H, ENC_H);
    interleave_vec<<<cdiv(4 * ENC_H, 256), 256, 0, stream>>>(ebF, ebF_i, ENC_H);
    interleave_vec<<<cdiv(4 * ENC_H, 256), 256, 0, stream>>>(ebR, ebR_i, ENC_H);
    build_wcat_int<<<cdiv(4 * DEC_H * KCAT, 256), 256, 0, stream>>>(dWih, dWhh, wcat_i);
    interleave_vec<<<cdiv(4 * DEC_H, 256), 256, 0, stream>>>(db, db_i, DEC_H);
    transpose_sq<<<cdiv(DEC_H * DEC_H, 256), 256, 0, stream>>>(aWi, aWiT, DEC_H);

    // ---- encoder input GEMMs ----
    launch_gemm_big_bias(emb_src, wihF_i, ebF_i, Gf, S_LEN * BATCH, 4 * ENC_H, EMB, 4 * ENC_H, stream);
    launch_gemm_big_bias(emb_src, wihR_i, ebR_i, Gr, S_LEN * BATCH, 4 * ENC_H, EMB, 4 * ENC_H, stream);

    // ---- persistent encoder ----
    enc_persistent<<<256, 256, 0, stream>>>(Gf, Gr, whhF_i, whhR_i, hF2, hR2, cF, cR,
                                            enc_out, &barcnt[0]);

    // ---- hoisted: encP = enc_out @ aWi ----
    launch_gemm_big(enc_out, aWiT, encP, S_LEN * BATCH, DEC_H, DEC_H, DEC_H, stream);

    // ---- cast generator weights into Gf's dead space ----
    cast_f32_bf16<<<cdiv((int)((size_t)TRG_V * DEC_H / 4), 256), 256, 0, stream>>>(gW, gWb, (size_t)TRG_V * DEC_H);

    // ---- decoder init ----
    dec_init2<<<cdiv(BATCH * DEC_H + BATCH * EMB, 256), 256, 0, stream>>>(
        hF2, cF, hR2, cR, trg, DEMBp, attn_cat, catA, cdec);

    // ---- persistent decoder ----
    dec_persistent<<<256, 256, 0, stream>>>(encP, enc_out, trg, DEMBp, aWo, wcat_i, db_i,
                                            attn_cat, catA, cdec, gpart, H_bf, &barcnt[1]);

    // ---- generator: MFMA bf16 GEMM ----
    {
        dim3 g(cdiv(TRG_V, 128), cdiv((T_LEN - 1) * BATCH, 128), 1);
        gemm_mfma_bf16<<<g, 256, 0, stream>>>(H_bf, gWb, gb, out + (size_t)BATCH * TRG_V,
                                              (T_LEN - 1) * BATCH, TRG_V, DEC_H, TRG_V);
    }

    // ---- in-place log_softmax over vocab ----
    log_softmax_rows<<<(T_LEN - 1) * BATCH, 256, 0, stream>>>(out + (size_t)BATCH * TRG_V, TRG_V);
}